// Round 14
// baseline (168.776 us; speedup 1.0000x reference)
//
#include <hip/hip_runtime.h>
#include <math.h>

#define T_IN 64
#define NPIX 16384
#define MAX_ITER 10
#define NSLOT 43
#define MAGIC 0x13579BDFu

typedef _Float16 half8_t __attribute__((ext_vector_type(8)));
typedef __fp16   fp16x2  __attribute__((ext_vector_type(2)));
typedef float    f32x4   __attribute__((ext_vector_type(4)));
typedef int      i32x4   __attribute__((ext_vector_type(4)));

union H8 { half8_t v; fp16x2 h2[4]; i32x4 i4; };

__device__ __forceinline__ float rcp_fast(float x) { return __builtin_amdgcn_rcpf(x); }

// exp2 fast path: v_exp_f32 either way; builtin guarded for compile safety.
__device__ __forceinline__ float exp2_fast(float x) {
#if __has_builtin(__builtin_amdgcn_exp2f)
    return __builtin_amdgcn_exp2f(x);
#else
    return exp2f(x);
#endif
}

__constant__ constexpr int NTMIN[16] = {0,0,0,0,0,1,1,1,1,2,2,2,2,3,3,3};
__constant__ constexpr int TOFS[16]  = {0,4,8,12,16,20,23,26,29,32,34,36,38,40,41,42};
// position of (kt, nt=NTMIN[kt]) within this parity class's compact reg list
__constant__ constexpr int POS[16]   = {0,0,4,4,8,8,12,11,15,14,18,16,20,18,22,19};
#define NBREG 23   // even parity: 23 slots; odd: 20 (3 regs unused)

// ---- field build for tile KT (compile-time KT -> all array idx constant) ----
// exp2-folded (c=-K*log2e, cT0, ch=0.5c per iter) + parallel chain muls.
template<int KT>
__device__ __forceinline__ void buildTile(float T0, float c, float cT0, float ch,
        float r, float r2, float r3, int q,
        const float (&d10s)[8], const float (&tse)[8],
        H8& F0h, H8& F1h, H8& F2h) {
    constexpr int J = KT >> 1;
    float  x[8];
    fp16x2 d1h[4];
    float  d10 = T0 - d10s[J];
    const fp16x2 c1 = {(__fp16)0.25f, (__fp16)0.25f};
    const fp16x2 c2 = {(__fp16)0.50f, (__fp16)0.50f};
    const fp16x2 c3 = {(__fp16)0.75f, (__fp16)0.75f};
    bool arith = true;
    if constexpr (KT == 0 || KT == 15) {
        bool flat = (KT == 0) ? (q == 0) : (q == 3);   // clamped tsh samples
        if (flat) {
            arith = false;
            #pragma unroll
            for (int j = 0; j < 8; ++j)
                x[j] = exp2_fast(fmaf(-c, tse[j], cT0));
            #pragma unroll
            for (int jj = 0; jj < 4; ++jj)
                d1h[jj] = __builtin_amdgcn_cvt_pkrtz(T0 - tse[2*jj],
                                                     T0 - tse[2*jj+1]);
        }
    }
    if (arith) {   // arithmetic tsh (step 0.125)
        float a0 = fmaf(-c, d10s[J], cT0);           // = c*d10
        x[0] = exp2_fast(a0);
        x[4] = exp2_fast(a0 - ch);                   // = x0 * r^4
        x[1] = x[0]*r; x[2] = x[0]*r2; x[3] = x[0]*r3;   // parallel, not chained
        x[5] = x[4]*r; x[6] = x[4]*r2; x[7] = x[4]*r3;
        fp16x2 D0 = __builtin_amdgcn_cvt_pkrtz(d10, d10 - 0.125f);
        d1h[0] = D0;
        d1h[1] = D0 - c1;
        d1h[2] = D0 - c2;
        d1h[3] = D0 - c3;
    }
    #pragma unroll
    for (int jj = 0; jj < 4; ++jj) {
        float s1a = rcp_fast(1.0f + x[2*jj]);
        float s1b = rcp_fast(1.0f + x[2*jj+1]);
        fp16x2 sh = __builtin_amdgcn_cvt_pkrtz(s1a, s1b);
        fp16x2 eh = sh - sh*sh;                  // v_pk f16
        F0h.h2[jj] = sh;
        F1h.h2[jj] = eh * d1h[jj];
        F2h.h2[jj] = eh;
    }
}

// ---- MFMA group for tile KT, compile-time NT recursion (const reg idx) ----
// BI: which slot of the 4-deep F ring holds this tile's fields.
template<int KT, int NT, int BI>
struct MfmaNT {
    static __device__ __forceinline__ void run(const i32x4 (&Breg)[NBREG],
            const H8 (&F0p)[4], const H8 (&F1p)[4], const H8 (&F2p)[4],
            f32x4 (&acc)[3][4]) {
        constexpr int idx = POS[KT] + NT - NTMIN[KT];
        H8 bh; bh.i4 = Breg[idx];
        if constexpr (KT < 2) {                 // first tile for either parity
            const f32x4 Z = (f32x4){0.f, 0.f, 0.f, 0.f};
            acc[0][NT] = __builtin_amdgcn_mfma_f32_16x16x32_f16(F0p[BI].v, bh.v, Z, 0, 0, 0);
            acc[1][NT] = __builtin_amdgcn_mfma_f32_16x16x32_f16(F1p[BI].v, bh.v, Z, 0, 0, 0);
            acc[2][NT] = __builtin_amdgcn_mfma_f32_16x16x32_f16(F2p[BI].v, bh.v, Z, 0, 0, 0);
        } else {
            acc[0][NT] = __builtin_amdgcn_mfma_f32_16x16x32_f16(F0p[BI].v, bh.v, acc[0][NT], 0, 0, 0);
            acc[1][NT] = __builtin_amdgcn_mfma_f32_16x16x32_f16(F1p[BI].v, bh.v, acc[1][NT], 0, 0, 0);
            acc[2][NT] = __builtin_amdgcn_mfma_f32_16x16x32_f16(F2p[BI].v, bh.v, acc[2][NT], 0, 0, 0);
        }
        if constexpr (NT + 1 < 4)
            MfmaNT<KT, NT+1, BI>::run(Breg, F0p, F1p, F2p, acc);
    }
};

// ---- batch-2 pipeline over this wave's 8 tiles (kt = H + 2*I) ----
// Stage S: build tiles I=2S+2,2S+3 (two INDEPENDENT chains -> 2x build ILP),
// then MFMA tiles I=2S,2S+1. F ring 4 deep, slot = I & 3.
template<int H, int S>
struct PipeB {
    static __device__ __forceinline__ void run(float T0, float c, float cT0, float ch,
            float r, float r2, float r3, int q,
            const float (&d10s)[8], const float (&tse)[8],
            const i32x4 (&Breg)[NBREG],
            H8 (&F0p)[4], H8 (&F1p)[4], H8 (&F2p)[4],
            f32x4 (&acc)[3][4]) {
        if constexpr (2*S+2 < 8)
            buildTile<H + 2*(2*S+2)>(T0, c, cT0, ch, r, r2, r3, q, d10s, tse,
                F0p[(2*S+2)&3], F1p[(2*S+2)&3], F2p[(2*S+2)&3]);
        if constexpr (2*S+3 < 8)
            buildTile<H + 2*(2*S+3)>(T0, c, cT0, ch, r, r2, r3, q, d10s, tse,
                F0p[(2*S+3)&3], F1p[(2*S+3)&3], F2p[(2*S+3)&3]);
        MfmaNT<H + 4*S,     NTMIN[H + 4*S],     (2*S)&3  >::run(Breg, F0p, F1p, F2p, acc);
        MfmaNT<H + 4*S + 2, NTMIN[H + 4*S + 2], (2*S+1)&3>::run(Breg, F0p, F1p, F2p, acc);
        if constexpr (S + 1 < 4)
            PipeB<H, S+1>::run(T0, c, cT0, ch, r, r2, r3, q, d10s, tse,
                               Breg, F0p, F1p, F2p, acc);
    }
};

template<int H>
__device__ __forceinline__ void pipeAcc(float T0, float c, float cT0, float ch,
        float r, float r2, float r3, int q,
        const float (&d10s)[8], const float (&tse)[8],
        const i32x4 (&Breg)[NBREG], f32x4 (&acc)[3][4]) {
    H8 F0p[4], F1p[4], F2p[4];
    buildTile<H>  (T0, c, cT0, ch, r, r2, r3, q, d10s, tse, F0p[0], F1p[0], F2p[0]);
    buildTile<H+2>(T0, c, cT0, ch, r, r2, r3, q, d10s, tse, F0p[1], F1p[1], F2p[1]);
    PipeB<H, 0>::run(T0, c, cT0, ch, r, r2, r3, q, d10s, tse, Breg, F0p, F1p, F2p, acc);
}

// ---- post-barrier B hoist: global (L2) -> registers, compile-time idx ----
template<int KT, int NT>
struct LoadNT {
    static __device__ __forceinline__ void run(const i32x4* __restrict__ Bgl,
                                               i32x4 (&Breg)[NBREG]) {
        Breg[POS[KT] + NT - NTMIN[KT]] = Bgl[(TOFS[KT] + NT - NTMIN[KT]) * 64];
        if constexpr (NT + 1 < 4) LoadNT<KT, NT+1>::run(Bgl, Breg);
    }
};
template<int KT>
struct LoadB {
    static __device__ __forceinline__ void run(const i32x4* __restrict__ Bgl,
                                               i32x4 (&Breg)[NBREG]) {
        LoadNT<KT, NTMIN[KT]>::run(Bgl, Breg);
        if constexpr (KT + 2 < 16) LoadB<KT+2>::run(Bgl, Breg);
    }
};

// ---- wave-pair acc exchange: H sends the components its partner finishes ----
template<int H>
__device__ __forceinline__ void sendHalf(const f32x4 (&acc)[3][4],
        float2* __restrict__ xch, int pair, int lane) {
    constexpr int SB = 2 - 2*H;
    float2* xw = xch + ((pair*2 + H)*12)*64 + lane;   // value-major: lane stride 8B
    #pragma unroll
    for (int i = 0; i < 3; ++i)
        #pragma unroll
        for (int nt = 0; nt < 4; ++nt)
            xw[(i*4+nt)*64] = make_float2(acc[i][nt][SB], acc[i][nt][SB+1]);
}

template<int H>
__device__ __forceinline__ void finishDots(f32x4 (&acc)[3][4],
        const float2* __restrict__ xch, float (&Gtab)[2][16][4],
        int pair, int lane, int q, int n,
        const float (&dch)[4][2], float A) {
    constexpr int KB = 2*H;
    const float2* xr = xch + ((pair*2 + (1-H))*12)*64 + lane;
    #pragma unroll
    for (int i = 0; i < 3; ++i)
        #pragma unroll
        for (int nt = 0; nt < 4; ++nt) {
            float2 v = xr[(i*4+nt)*64];
            acc[i][nt][KB]   += v.x;
            acc[i][nt][KB+1] += v.y;
        }
    float Ap0 = __shfl(A, q*4 + KB);
    float Ap1 = __shfl(A, q*4 + KB + 1);
    float SA0=0.f,SK0=0.f,ST0=0.f, SA1=0.f,SK1=0.f,ST1=0.f;
    #pragma unroll
    for (int nt = 0; nt < 4; ++nt) {
        float Y0 = acc[0][nt][KB], Y1 = acc[1][nt][KB], Y2 = acc[2][nt][KB];
        float rr = fmaf(Ap0, Y0, -dch[nt][0]);           // est - dc
        SA0 = fmaf(rr, Y0, SA0); SK0 = fmaf(rr, Y1, SK0); ST0 = fmaf(rr, Y2, ST0);
        float y0 = acc[0][nt][KB+1], y1 = acc[1][nt][KB+1], y2 = acc[2][nt][KB+1];
        float r2 = fmaf(Ap1, y0, -dch[nt][1]);
        SA1 = fmaf(r2, y0, SA1); SK1 = fmaf(r2, y1, SK1); ST1 = fmaf(r2, y2, ST1);
    }
    #pragma unroll
    for (int m = 1; m < 16; m <<= 1) {
        SA0 += __shfl_xor(SA0, m); SK0 += __shfl_xor(SK0, m); ST0 += __shfl_xor(ST0, m);
        SA1 += __shfl_xor(SA1, m); SK1 += __shfl_xor(SK1, m); ST1 += __shfl_xor(ST1, m);
    }
    if (n == 0) {
        float* g = Gtab[pair][q*4 + KB];
        g[0] = SA0; g[1] = SK0; g[2] = ST0;
    }
    if (n == 1) {
        float* g = Gtab[pair][q*4 + KB + 1];
        g[0] = SA1; g[1] = SK1; g[2] = ST1;
    }
}

// ---------------------------------------------------------------- all -------
// R26: single dispatch, grid 512 x 256 (2 blocks/CU, fully resident).
// Prep inlined (tshs/aifos local in LDS -> no tshg round-trip; dch read once
// and reused for C_dc partial AND the loop; B built once by blocks 0..42 ->
// Bg + writer threadfence). R0's proven flag-spin grid barrier (512 flags).
// Loop is the byte-identical verified R21 kernel (B in registers, batch-2
// builds, exp2-fold). Saves one launch + inter-kernel drain (~5 us).
__global__ __launch_bounds__(256, 2) void k_all(
        const float* __restrict__ ctc,  const float* __restrict__ aif,
        const float* __restrict__ timev,const float* __restrict__ lam,
        const float* __restrict__ eta,  unsigned int* __restrict__ flags,
        i32x4* __restrict__ Bg,         f32x4* __restrict__ partials,
        float* __restrict__ out) {
    __shared__ float tshs[512];        // 2 KB
    __shared__ float aifos[512];       // 2 KB
    __shared__ float a_s[64], t_s[64];
    __shared__ f32x4 red[4];
    __shared__ float2 xch[2*2*12*64];  // 24 KB acc exchange
    __shared__ float Gtab[2][16][4];   // per-pair per-pixel gradients

    const int tid  = threadIdx.x;
    const int lane = tid & 63;
    const int wid  = tid >> 6;         // 0..3
    const int hh   = wid & 1;          // kt parity handled by this wave
    const int pair = wid >> 1;         // pixel group 0..1
    const int q = lane >> 4, n = lane & 15;
    const int pixbase = blockIdx.x * 32 + pair * 16;
    const int mypix   = pixbase + n;

    // ---- phase A: local tshs/aifos ----
    if (tid < 64) { a_s[tid] = aif[tid]; t_s[tid] = timev[tid]; }
    float A  = eta[mypix];
    float K  = eta[NPIX + mypix];
    float T0 = eta[2*NPIX + mypix];
    const float pA = A, pK = K, pT = T0;
    __syncthreads();
    {
        float m5a = 0.2f * (a_s[0]+a_s[1]+a_s[2]+a_s[3]+a_s[4]);
        float t16;
        {   // t_os[16]: x = (16-3.5)/8 = 1.5625
            float xx = 1.5625f; int i0 = (int)xx; float f = xx - (float)i0;
            t16 = t_s[i0]*(1.0f-f) + t_s[i0+1]*f;
        }
        #pragma unroll
        for (int rep = 0; rep < 2; ++rep) {
            int i = tid + 256*rep;
            float x = ((float)i - 3.5f) * 0.125f;
            float ao, to;
            if (x <= 0.0f)       { ao = a_s[0]  - m5a; to = t_s[0];  }
            else if (x >= 63.0f) { ao = a_s[63] - m5a; to = t_s[63]; }
            else {
                int i0 = (int)x; float f = x - (float)i0;
                ao = (a_s[i0]-m5a)*(1.0f-f) + (a_s[i0+1]-m5a)*f;
                to = t_s[i0]*(1.0f-f) + t_s[i0+1]*f;
            }
            aifos[i] = ao;
            tshs[i]  = to - t16;
        }
    }
    __syncthreads();

    // ---- B build: block s (< NSLOT) computes slot s -> Bg (once, global) ----
    if (blockIdx.x < NSLOT && tid < 64) {
        int slot = blockIdx.x, l = tid;
        int kt, nt;
        if (slot < 20)      { kt = slot >> 2; nt = slot & 3; }
        else if (slot < 32) { int s = slot - 20; int d3 = s / 3; kt = 5 + d3; nt = 1 + (s - 3*d3); }
        else if (slot < 40) { int s = slot - 32; kt = 9 + (s >> 1); nt = 2 + (s & 1); }
        else                { kt = 13 + (slot - 40); nt = 3; }
        int kbase = 32*kt + 8*(l >> 4);
        int m = 16 + 8 * (16*nt + (l & 15));   // m_d = 16+8d
        H8 bh;
        #pragma unroll
        for (int jj = 0; jj < 4; ++jj) {
            float v[2];
            #pragma unroll
            for (int h = 0; h < 2; ++h) {
                int k  = kbase + 2*jj + h;
                int ai = m - k;
                float s2 = 1.0f / (1.0f + __expf(-500.0f * tshs[k]));
                v[h] = (ai >= 0 && ai < 512) ? s2 * aifos[ai] * 0.125f : 0.0f;
            }
            bh.h2[jj] = (fp16x2){(__fp16)v[0], (__fp16)v[1]};   // RTN
        }
        Bg[slot*64 + l] = bh.i4;
        __threadfence();   // writer-side: publish Bg before block's flag release
    }

    // ---- dch from ctc (read once; reused for C_dc partial AND loop) ----
    float dch[4][2];
    #pragma unroll
    for (int j = 0; j < 2; ++j) {
        const float* cp = ctc + (pixbase + q*4 + 2*hh + j) * T_IN;
        float m5 = 0.2f * (cp[0]+cp[1]+cp[2]+cp[3]+cp[4]);
        #pragma unroll
        for (int nt = 0; nt < 4; ++nt) {
            int d = nt*16 + n;
            float cc = cp[d] - m5;
            float cm = cp[(d > 0) ? d-1 : 0] - m5;
            dch[nt][j] = (d == 0) ? cc : (0.4375f*cm + 0.5625f*cc);
        }
    }

    // ---- block partials: C_dc from dch (each (row,d) once across waves);
    // eta squares: pixel on 8 lanes (4 q x 2 hh) -> /8 ----
    {
        float vs = 0.f;
        #pragma unroll
        for (int nt = 0; nt < 4; ++nt)
            #pragma unroll
            for (int j = 0; j < 2; ++j) vs += dch[nt][j]*dch[nt][j];
        f32x4 pv = (f32x4){vs, 0.125f*A*A, 0.125f*K*K, 0.125f*T0*T0};
        #pragma unroll
        for (int m = 1; m < 64; m <<= 1) {
            pv.x += __shfl_xor(pv.x, m); pv.y += __shfl_xor(pv.y, m);
            pv.z += __shfl_xor(pv.z, m); pv.w += __shfl_xor(pv.w, m);
        }
        if (lane == 0) red[wid] = pv;
    }
    __syncthreads();   // red ready; also orders B-build stores before flag
    if (tid == 0) {
        partials[blockIdx.x] = red[0] + red[1] + red[2] + red[3];
        __threadfence();
        __hip_atomic_store(&flags[blockIdx.x], MAGIC, __ATOMIC_RELEASE,
                           __HIP_MEMORY_SCOPE_AGENT);
    }

    // ---- seeds from local tshs (LDS): chain seeds for this wave's tiles ----
    float d10s[8];
    #pragma unroll
    for (int j = 0; j < 8; ++j) d10s[j] = tshs[32*(2*j + hh) + 8*q];
    float tse[8];
    {
        const float* tb = hh ? (tshs + 480) : tshs;   // even: head, odd: tail
        #pragma unroll
        for (int j = 0; j < 8; ++j) tse[j] = tb[8*q + j];
    }

    // ---- grid barrier: thread t watches flags[t] and flags[t+256] ----
    while (__hip_atomic_load(&flags[tid], __ATOMIC_ACQUIRE,
                             __HIP_MEMORY_SCOPE_AGENT) != MAGIC)
        __builtin_amdgcn_s_sleep(2);
    while (__hip_atomic_load(&flags[tid + 256], __ATOMIC_ACQUIRE,
                             __HIP_MEMORY_SCOPE_AGENT) != MAGIC)
        __builtin_amdgcn_s_sleep(2);
    __syncthreads();

    // ---- hoist B into registers (Bg valid after barrier; L2-resident) ----
    const i32x4* Bgl = Bg + lane;
    i32x4 Breg[NBREG];
    if (hh == 0) LoadB<0>::run(Bgl, Breg);
    else         LoadB<1>::run(Bgl, Breg);

    // ---- reduce the 512 completed partials ----
    f32x4 tot = partials[lane]       + partials[64+lane]
              + partials[128+lane]   + partials[192+lane]
              + partials[256+lane]   + partials[320+lane]
              + partials[384+lane]   + partials[448+lane];
    #pragma unroll
    for (int m = 1; m < 64; m <<= 1) {
        tot.x += __shfl_xor(tot.x, m); tot.y += __shfl_xor(tot.y, m);
        tot.z += __shfl_xor(tot.z, m); tot.w += __shfl_xor(tot.w, m);
    }
    float spl;
    {
        float xl = lam[0];
        spl = (xl > 0.0f) ? (xl + log1pf(__expf(-xl))) : log1pf(__expf(xl));
    }
    const float cdc2 = 2.0f / tot.x;
    const float rgA  = 2.0f * spl / tot.y;
    const float rgK  = 2.0f * spl / tot.z;
    const float rgT  = 2.0f * spl / tot.w;

    #pragma unroll 1
    for (int it = 0; it < MAX_ITER; ++it) {
        // per-iter exp2-folded constants
        float c   = -1.44269504f * K;      // = nK * log2(e)
        float cT0 = c * T0;
        float ch  = 0.5f * c;
        float r   = exp2_fast(0.18033688f * K);   // exp(0.125K)
        float r2  = r * r;
        float r3  = r2 * r;

        f32x4 acc[3][4];
        if (hh == 0) {
            pipeAcc<0>(T0, c, cT0, ch, r, r2, r3, q, d10s, tse, Breg, acc);
            sendHalf<0>(acc, xch, pair, lane);
        } else {
            pipeAcc<1>(T0, c, cT0, ch, r, r2, r3, q, d10s, tse, Breg, acc);
            sendHalf<1>(acc, xch, pair, lane);
        }
        __syncthreads();
        if (hh == 0) finishDots<0>(acc, xch, Gtab, pair, lane, q, n, dch, A);
        else         finishDots<1>(acc, xch, Gtab, pair, lane, q, n, dch, A);
        __syncthreads();

        const float GA = Gtab[pair][n][0];
        const float GK = Gtab[pair][n][1];
        const float GT = Gtab[pair][n][2];
        float gA = fmaf(rgA, A  - pA, cdc2 * GA)         + 2.0f * fminf(A,  0.f);
        float gK = fmaf(rgK, K  - pK, cdc2 * A * GK)     + 2.0f * fminf(K,  0.f);
        float gT = fmaf(rgT, T0 - pT, cdc2 * A * K * GT) + 2.0f * fminf(T0, 0.f);
        A  -= 0.1f * gA;
        K  -= 0.1f * gK;
        T0 -= 0.1f * gT;
    }

    if (hh == 0 && lane < 16) {
        out[mypix]          = A;
        out[NPIX + mypix]   = K;
        out[2*NPIX + mypix] = T0;
    }
}

// -------------------------------------------------------------- launch ------
extern "C" void kernel_launch(void* const* d_in, const int* in_sizes, int n_in,
                              void* d_out, int out_size, void* d_ws, size_t ws_size,
                              hipStream_t stream) {
    const float* ctc   = (const float*)d_in[0];
    const float* aif   = (const float*)d_in[1];
    const float* timev = (const float*)d_in[2];
    const float* eta   = (const float*)d_in[4];
    const float* lam   = (const float*)d_in[5];
    float* out = (float*)d_out;
    // ws layout: [0..8191]      f32x4 partials[512]
    //            [8192..10239]  u32 flags[512]   (poison 0xAA... != MAGIC)
    //            [10240..54271] i32x4 Bg[NSLOT*64]
    f32x4*        partials = (f32x4*)d_ws;
    unsigned int* flags    = (unsigned int*)((char*)d_ws + 8192);
    i32x4*        Bg       = (i32x4*)((char*)d_ws + 10240);

    k_all<<<NPIX / 32, 256, 0, stream>>>(ctc, aif, timev, lam, eta,
                                         flags, Bg, partials, out);
}

// Round 15
// 102.974 us; speedup vs baseline: 1.6390x; 1.6390x over previous
//
#include <hip/hip_runtime.h>
#include <math.h>

#define T_IN 64
#define NPIX 16384
#define MAX_ITER 10
#define NSLOT 43

typedef _Float16 half8_t __attribute__((ext_vector_type(8)));
typedef __fp16   fp16x2  __attribute__((ext_vector_type(2)));
typedef float    f32x4   __attribute__((ext_vector_type(4)));
typedef int      i32x4   __attribute__((ext_vector_type(4)));

union H8 { half8_t v; fp16x2 h2[4]; i32x4 i4; };

__device__ __forceinline__ float rcp_fast(float x) { return __builtin_amdgcn_rcpf(x); }

// exp2 fast path: v_exp_f32 either way; builtin guarded for compile safety.
__device__ __forceinline__ float exp2_fast(float x) {
#if __has_builtin(__builtin_amdgcn_exp2f)
    return __builtin_amdgcn_exp2f(x);
#else
    return exp2f(x);
#endif
}

__constant__ constexpr int NTMIN[16] = {0,0,0,0,0,1,1,1,1,2,2,2,2,3,3,3};
__constant__ constexpr int TOFS[16]  = {0,4,8,12,16,20,23,26,29,32,34,36,38,40,41,42};
// position of (kt, nt=NTMIN[kt]) within this parity class's compact reg list
__constant__ constexpr int POS[16]   = {0,0,4,4,8,8,12,11,15,14,18,16,20,18,22,19};
#define NBREG 23   // even parity: 23 slots; odd: 20 (3 regs unused)

// ---- field build for tile KT (compile-time KT -> all array idx constant) ----
// exp2-folded (c=-K*log2e, cT0, ch=0.5c per iter) + parallel chain muls.
template<int KT>
__device__ __forceinline__ void buildTile(float T0, float c, float cT0, float ch,
        float r, float r2, float r3, int q,
        const float (&d10s)[8], const float (&tse)[8],
        H8& F0h, H8& F1h, H8& F2h) {
    constexpr int J = KT >> 1;
    float  x[8];
    fp16x2 d1h[4];
    float  d10 = T0 - d10s[J];
    const fp16x2 c1 = {(__fp16)0.25f, (__fp16)0.25f};
    const fp16x2 c2 = {(__fp16)0.50f, (__fp16)0.50f};
    const fp16x2 c3 = {(__fp16)0.75f, (__fp16)0.75f};
    bool arith = true;
    if constexpr (KT == 0 || KT == 15) {
        bool flat = (KT == 0) ? (q == 0) : (q == 3);   // clamped tsh samples
        if (flat) {
            arith = false;
            #pragma unroll
            for (int j = 0; j < 8; ++j)
                x[j] = exp2_fast(fmaf(-c, tse[j], cT0));
            #pragma unroll
            for (int jj = 0; jj < 4; ++jj)
                d1h[jj] = __builtin_amdgcn_cvt_pkrtz(T0 - tse[2*jj],
                                                     T0 - tse[2*jj+1]);
        }
    }
    if (arith) {   // arithmetic tsh (step 0.125)
        float a0 = fmaf(-c, d10s[J], cT0);           // = c*d10
        x[0] = exp2_fast(a0);
        x[4] = exp2_fast(a0 - ch);                   // = x0 * r^4
        x[1] = x[0]*r; x[2] = x[0]*r2; x[3] = x[0]*r3;   // parallel, not chained
        x[5] = x[4]*r; x[6] = x[4]*r2; x[7] = x[4]*r3;
        fp16x2 D0 = __builtin_amdgcn_cvt_pkrtz(d10, d10 - 0.125f);
        d1h[0] = D0;
        d1h[1] = D0 - c1;
        d1h[2] = D0 - c2;
        d1h[3] = D0 - c3;
    }
    #pragma unroll
    for (int jj = 0; jj < 4; ++jj) {
        float s1a = rcp_fast(1.0f + x[2*jj]);
        float s1b = rcp_fast(1.0f + x[2*jj+1]);
        fp16x2 sh = __builtin_amdgcn_cvt_pkrtz(s1a, s1b);
        fp16x2 eh = sh - sh*sh;                  // v_pk f16
        F0h.h2[jj] = sh;
        F1h.h2[jj] = eh * d1h[jj];
        F2h.h2[jj] = eh;
    }
}

// ---- MFMA group for tile KT, compile-time NT recursion (const reg idx) ----
// BI: which slot of the 4-deep F ring holds this tile's fields.
template<int KT, int NT, int BI>
struct MfmaNT {
    static __device__ __forceinline__ void run(const i32x4 (&Breg)[NBREG],
            const H8 (&F0p)[4], const H8 (&F1p)[4], const H8 (&F2p)[4],
            f32x4 (&acc)[3][4]) {
        constexpr int idx = POS[KT] + NT - NTMIN[KT];
        H8 bh; bh.i4 = Breg[idx];
        if constexpr (KT < 2) {                 // first tile for either parity
            const f32x4 Z = (f32x4){0.f, 0.f, 0.f, 0.f};
            acc[0][NT] = __builtin_amdgcn_mfma_f32_16x16x32_f16(F0p[BI].v, bh.v, Z, 0, 0, 0);
            acc[1][NT] = __builtin_amdgcn_mfma_f32_16x16x32_f16(F1p[BI].v, bh.v, Z, 0, 0, 0);
            acc[2][NT] = __builtin_amdgcn_mfma_f32_16x16x32_f16(F2p[BI].v, bh.v, Z, 0, 0, 0);
        } else {
            acc[0][NT] = __builtin_amdgcn_mfma_f32_16x16x32_f16(F0p[BI].v, bh.v, acc[0][NT], 0, 0, 0);
            acc[1][NT] = __builtin_amdgcn_mfma_f32_16x16x32_f16(F1p[BI].v, bh.v, acc[1][NT], 0, 0, 0);
            acc[2][NT] = __builtin_amdgcn_mfma_f32_16x16x32_f16(F2p[BI].v, bh.v, acc[2][NT], 0, 0, 0);
        }
        if constexpr (NT + 1 < 4)
            MfmaNT<KT, NT+1, BI>::run(Breg, F0p, F1p, F2p, acc);
    }
};

// ---- batch-2 pipeline over this wave's 8 tiles (kt = H + 2*I) ----
// Stage S: build tiles I=2S+2,2S+3 (two INDEPENDENT chains -> 2x build ILP),
// then MFMA tiles I=2S,2S+1. F ring 4 deep, slot = I & 3.
template<int H, int S>
struct PipeB {
    static __device__ __forceinline__ void run(float T0, float c, float cT0, float ch,
            float r, float r2, float r3, int q,
            const float (&d10s)[8], const float (&tse)[8],
            const i32x4 (&Breg)[NBREG],
            H8 (&F0p)[4], H8 (&F1p)[4], H8 (&F2p)[4],
            f32x4 (&acc)[3][4]) {
        if constexpr (2*S+2 < 8)
            buildTile<H + 2*(2*S+2)>(T0, c, cT0, ch, r, r2, r3, q, d10s, tse,
                F0p[(2*S+2)&3], F1p[(2*S+2)&3], F2p[(2*S+2)&3]);
        if constexpr (2*S+3 < 8)
            buildTile<H + 2*(2*S+3)>(T0, c, cT0, ch, r, r2, r3, q, d10s, tse,
                F0p[(2*S+3)&3], F1p[(2*S+3)&3], F2p[(2*S+3)&3]);
        MfmaNT<H + 4*S,     NTMIN[H + 4*S],     (2*S)&3  >::run(Breg, F0p, F1p, F2p, acc);
        MfmaNT<H + 4*S + 2, NTMIN[H + 4*S + 2], (2*S+1)&3>::run(Breg, F0p, F1p, F2p, acc);
        if constexpr (S + 1 < 4)
            PipeB<H, S+1>::run(T0, c, cT0, ch, r, r2, r3, q, d10s, tse,
                               Breg, F0p, F1p, F2p, acc);
    }
};

template<int H>
__device__ __forceinline__ void pipeAcc(float T0, float c, float cT0, float ch,
        float r, float r2, float r3, int q,
        const float (&d10s)[8], const float (&tse)[8],
        const i32x4 (&Breg)[NBREG], f32x4 (&acc)[3][4]) {
    H8 F0p[4], F1p[4], F2p[4];
    buildTile<H>  (T0, c, cT0, ch, r, r2, r3, q, d10s, tse, F0p[0], F1p[0], F2p[0]);
    buildTile<H+2>(T0, c, cT0, ch, r, r2, r3, q, d10s, tse, F0p[1], F1p[1], F2p[1]);
    PipeB<H, 0>::run(T0, c, cT0, ch, r, r2, r3, q, d10s, tse, Breg, F0p, F1p, F2p, acc);
}

// ---- pre-loop B hoist: global (L2) -> registers, compile-time indices ----
template<int KT, int NT>
struct LoadNT {
    static __device__ __forceinline__ void run(const i32x4* __restrict__ Bgl,
                                               i32x4 (&Breg)[NBREG]) {
        Breg[POS[KT] + NT - NTMIN[KT]] = Bgl[(TOFS[KT] + NT - NTMIN[KT]) * 64];
        if constexpr (NT + 1 < 4) LoadNT<KT, NT+1>::run(Bgl, Breg);
    }
};
template<int KT>
struct LoadB {
    static __device__ __forceinline__ void run(const i32x4* __restrict__ Bgl,
                                               i32x4 (&Breg)[NBREG]) {
        LoadNT<KT, NTMIN[KT]>::run(Bgl, Breg);
        if constexpr (KT + 2 < 16) LoadB<KT+2>::run(Bgl, Breg);
    }
};

// ---- wave-pair acc exchange: H sends the components its partner finishes ----
template<int H>
__device__ __forceinline__ void sendHalf(const f32x4 (&acc)[3][4],
        float2* __restrict__ xch, int pair, int lane) {
    constexpr int SB = 2 - 2*H;
    float2* xw = xch + ((pair*2 + H)*12)*64 + lane;   // value-major: lane stride 8B
    #pragma unroll
    for (int i = 0; i < 3; ++i)
        #pragma unroll
        for (int nt = 0; nt < 4; ++nt)
            xw[(i*4+nt)*64] = make_float2(acc[i][nt][SB], acc[i][nt][SB+1]);
}

template<int H>
__device__ __forceinline__ void finishDots(f32x4 (&acc)[3][4],
        const float2* __restrict__ xch, float (&Gtab)[2][16][4],
        int pair, int lane, int q, int n,
        const float (&dch)[4][2], float A) {
    constexpr int KB = 2*H;
    const float2* xr = xch + ((pair*2 + (1-H))*12)*64 + lane;
    #pragma unroll
    for (int i = 0; i < 3; ++i)
        #pragma unroll
        for (int nt = 0; nt < 4; ++nt) {
            float2 v = xr[(i*4+nt)*64];
            acc[i][nt][KB]   += v.x;
            acc[i][nt][KB+1] += v.y;
        }
    float Ap0 = __shfl(A, q*4 + KB);
    float Ap1 = __shfl(A, q*4 + KB + 1);
    float SA0=0.f,SK0=0.f,ST0=0.f, SA1=0.f,SK1=0.f,ST1=0.f;
    #pragma unroll
    for (int nt = 0; nt < 4; ++nt) {
        float Y0 = acc[0][nt][KB], Y1 = acc[1][nt][KB], Y2 = acc[2][nt][KB];
        float rr = fmaf(Ap0, Y0, -dch[nt][0]);           // est - dc
        SA0 = fmaf(rr, Y0, SA0); SK0 = fmaf(rr, Y1, SK0); ST0 = fmaf(rr, Y2, ST0);
        float y0 = acc[0][nt][KB+1], y1 = acc[1][nt][KB+1], y2 = acc[2][nt][KB+1];
        float r2 = fmaf(Ap1, y0, -dch[nt][1]);
        SA1 = fmaf(r2, y0, SA1); SK1 = fmaf(r2, y1, SK1); ST1 = fmaf(r2, y2, ST1);
    }
    #pragma unroll
    for (int m = 1; m < 16; m <<= 1) {
        SA0 += __shfl_xor(SA0, m); SK0 += __shfl_xor(SK0, m); ST0 += __shfl_xor(ST0, m);
        SA1 += __shfl_xor(SA1, m); SK1 += __shfl_xor(SK1, m); ST1 += __shfl_xor(ST1, m);
    }
    if (n == 0) {
        float* g = Gtab[pair][q*4 + KB];
        g[0] = SA0; g[1] = SK0; g[2] = ST0;
    }
    if (n == 1) {
        float* g = Gtab[pair][q*4 + KB + 1];
        g[0] = SA1; g[1] = SK1; g[2] = ST1;
    }
}

// ---------------------------------------------------------------- prep ------
// Grid 512 x 256 thr, 32 px/block -> 2 blocks/CU on the latency-bound
// cold-ctc pass. Waves split (pixel-subgroup x nt-half). B built once -> ws.
__global__ __launch_bounds__(256, 2) void k_prep(
        const float* __restrict__ ctc,  const float* __restrict__ aif,
        const float* __restrict__ timev,const float* __restrict__ eta,
        float* __restrict__ tshg, i32x4* __restrict__ Bg,
        f32x4* __restrict__ partials) {
    __shared__ float tshs[512];
    __shared__ float aifos[512];
    __shared__ float a_s[64], t_s[64];
    __shared__ f32x4 red[4];

    const int tid  = threadIdx.x;
    const int lane = tid & 63;
    const int wid  = tid >> 6;
    const int q = lane >> 4, n = lane & 15;
    const int pixbase = blockIdx.x * 32 + (wid & 1) * 16;
    const int ntb     = (wid >> 1) * 2;          // nt half: {0,1} or {2,3}
    const int mypix   = pixbase + n;

    if (tid < 64) { a_s[tid] = aif[tid]; t_s[tid] = timev[tid]; }
    float A  = eta[mypix];
    float K  = eta[NPIX + mypix];
    float T0 = eta[2*NPIX + mypix];
    __syncthreads();
    {
        float m5a = 0.2f * (a_s[0]+a_s[1]+a_s[2]+a_s[3]+a_s[4]);
        float t16;
        {   // t_os[16]: x = (16-3.5)/8 = 1.5625
            float xx = 1.5625f; int i0 = (int)xx; float f = xx - (float)i0;
            t16 = t_s[i0]*(1.0f-f) + t_s[i0+1]*f;
        }
        #pragma unroll
        for (int rep = 0; rep < 2; ++rep) {
            int i = tid + 256*rep;
            float x = ((float)i - 3.5f) * 0.125f;
            float ao, to;
            if (x <= 0.0f)       { ao = a_s[0]  - m5a; to = t_s[0];  }
            else if (x >= 63.0f) { ao = a_s[63] - m5a; to = t_s[63]; }
            else {
                int i0 = (int)x; float f = x - (float)i0;
                ao = (a_s[i0]-m5a)*(1.0f-f) + (a_s[i0+1]-m5a)*f;
                to = t_s[i0]*(1.0f-f) + t_s[i0+1]*f;
            }
            aifos[i] = ao;
            tshs[i]  = to - t16;
            if (blockIdx.x == 0) tshg[i] = to - t16;
        }
    }
    __syncthreads();

    // ---- B tile build: block s (< NSLOT) computes slot s, threads 0..63 ----
    if (blockIdx.x < NSLOT && tid < 64) {
        int slot = blockIdx.x, l = tid;
        int kt, nt;
        if (slot < 20)      { kt = slot >> 2; nt = slot & 3; }
        else if (slot < 32) { int s = slot - 20; int d3 = s / 3; kt = 5 + d3; nt = 1 + (s - 3*d3); }
        else if (slot < 40) { int s = slot - 32; kt = 9 + (s >> 1); nt = 2 + (s & 1); }
        else                { kt = 13 + (slot - 40); nt = 3; }
        int kbase = 32*kt + 8*(l >> 4);
        int m = 16 + 8 * (16*nt + (l & 15));   // m_d = 16+8d
        H8 bh;
        #pragma unroll
        for (int jj = 0; jj < 4; ++jj) {
            float v[2];
            #pragma unroll
            for (int h = 0; h < 2; ++h) {
                int k  = kbase + 2*jj + h;
                int ai = m - k;
                float s2 = 1.0f / (1.0f + __expf(-500.0f * tshs[k]));
                v[h] = (ai >= 0 && ai < 512) ? s2 * aifos[ai] * 0.125f : 0.0f;
            }
            bh.h2[jj] = (fp16x2){(__fp16)v[0], (__fp16)v[1]};   // RTN
        }
        Bg[slot*64 + l] = bh.i4;
    }

    // ---- ctc_dc partials: this wave covers its 16 rows x its 2 nt ----
    float vs = 0.f;
    #pragma unroll
    for (int reg = 0; reg < 4; ++reg) {
        const float* cp = ctc + (pixbase + q*4 + reg) * T_IN;
        float m5 = 0.2f * (cp[0]+cp[1]+cp[2]+cp[3]+cp[4]);
        #pragma unroll
        for (int a = 0; a < 2; ++a) {
            int d = (ntb + a)*16 + n;
            float cc = cp[d] - m5;
            float cm = cp[(d > 0) ? d-1 : 0] - m5;
            float dc = (d == 0) ? cc : (0.4375f*cm + 0.5625f*cc);
            vs += dc * dc;
        }
    }
    // each pixel appears on 8 lanes (4 q x 2 nt-halves) -> eta squares / 8
    {
        f32x4 pv = (f32x4){vs, 0.125f*A*A, 0.125f*K*K, 0.125f*T0*T0};
        #pragma unroll
        for (int m = 1; m < 64; m <<= 1) {
            pv.x += __shfl_xor(pv.x, m); pv.y += __shfl_xor(pv.y, m);
            pv.z += __shfl_xor(pv.z, m); pv.w += __shfl_xor(pv.w, m);
        }
        if (lane == 0) red[wid] = pv;
    }
    __syncthreads();
    if (tid == 0)
        partials[blockIdx.x] = red[0] + red[1] + red[2] + red[3];
}

// ---------------------------------------------------------------- iter ------
// Verified best (R21/R23 lineage): kt-parity wave pair, B in registers
// (R20), batch-2 builds + exp2-fold (R21), 512-entry partials reduce.
// 2 waves/SIMD, VGPR 128, no spill — the structure's verified floor.
// R26 lesson: in-kernel grid barrier at 512 blocks costs ~70 us in
// cross-XCD flag contention — stream-ordered two-dispatch is strictly better.
__global__ __launch_bounds__(256, 2) void k_iter(
        const float* __restrict__ ctc,  const float* __restrict__ lam,
        const float* __restrict__ eta,  const float* __restrict__ tshg,
        const i32x4* __restrict__ Bg,   const f32x4* __restrict__ partials,
        float* __restrict__ out) {
    __shared__ float2 xch[2*2*12*64];  // 24 KB acc exchange
    __shared__ float Gtab[2][16][4];   // per-pair per-pixel gradients

    const int tid  = threadIdx.x;
    const int lane = tid & 63;
    const int wid  = tid >> 6;         // 0..3
    const int hh   = wid & 1;          // kt parity handled by this wave
    const int pair = wid >> 1;         // pixel group 0..1
    const int q = lane >> 4, n = lane & 15;
    const int pixbase = blockIdx.x * 32 + pair * 16;
    const int mypix   = pixbase + n;

    // ---- hoist B into registers (issue early; covered by setup below) ----
    const i32x4* Bgl = Bg + lane;
    i32x4 Breg[NBREG];
    if (hh == 0) LoadB<0>::run(Bgl, Breg);
    else         LoadB<1>::run(Bgl, Breg);

    float A  = eta[mypix];
    float K  = eta[NPIX + mypix];
    float T0 = eta[2*NPIX + mypix];
    const float pA = A, pK = K, pT = T0;

    // ctc_dc rows this wave finishes: dch[nt][j] = dc[p=q*4+2*hh+j][d=nt*16+n]
    float dch[4][2];
    #pragma unroll
    for (int j = 0; j < 2; ++j) {
        const float* cp = ctc + (pixbase + q*4 + 2*hh + j) * T_IN;
        float m5 = 0.2f * (cp[0]+cp[1]+cp[2]+cp[3]+cp[4]);
        #pragma unroll
        for (int nt = 0; nt < 4; ++nt) {
            int d = nt*16 + n;
            float cc = cp[d] - m5;
            float cm = cp[(d > 0) ? d-1 : 0] - m5;
            dch[nt][j] = (d == 0) ? cc : (0.4375f*cm + 0.5625f*cc);
        }
    }

    // ---- seeds from L2 (one-time): chain seeds for this wave's 8 tiles ----
    float d10s[8];
    #pragma unroll
    for (int j = 0; j < 8; ++j) d10s[j] = tshg[32*(2*j + hh) + 8*q];
    float tse[8];
    {
        const float* tb = hh ? (tshg + 480) : tshg;   // even: head, odd: tail
        #pragma unroll
        for (int j = 0; j < 8; ++j) tse[j] = tb[8*q + j];
    }

    // ---- reduce the 512 completed partials ----
    f32x4 tot = partials[lane]       + partials[64+lane]
              + partials[128+lane]   + partials[192+lane]
              + partials[256+lane]   + partials[320+lane]
              + partials[384+lane]   + partials[448+lane];
    #pragma unroll
    for (int m = 1; m < 64; m <<= 1) {
        tot.x += __shfl_xor(tot.x, m); tot.y += __shfl_xor(tot.y, m);
        tot.z += __shfl_xor(tot.z, m); tot.w += __shfl_xor(tot.w, m);
    }
    float spl;
    {
        float xl = lam[0];
        spl = (xl > 0.0f) ? (xl + log1pf(__expf(-xl))) : log1pf(__expf(xl));
    }
    const float cdc2 = 2.0f / tot.x;
    const float rgA  = 2.0f * spl / tot.y;
    const float rgK  = 2.0f * spl / tot.z;
    const float rgT  = 2.0f * spl / tot.w;

    #pragma unroll 1
    for (int it = 0; it < MAX_ITER; ++it) {
        // per-iter exp2-folded constants
        float c   = -1.44269504f * K;      // = nK * log2(e)
        float cT0 = c * T0;
        float ch  = 0.5f * c;
        float r   = exp2_fast(0.18033688f * K);   // exp(0.125K)
        float r2  = r * r;
        float r3  = r2 * r;

        f32x4 acc[3][4];
        if (hh == 0) {
            pipeAcc<0>(T0, c, cT0, ch, r, r2, r3, q, d10s, tse, Breg, acc);
            sendHalf<0>(acc, xch, pair, lane);
        } else {
            pipeAcc<1>(T0, c, cT0, ch, r, r2, r3, q, d10s, tse, Breg, acc);
            sendHalf<1>(acc, xch, pair, lane);
        }
        __syncthreads();
        if (hh == 0) finishDots<0>(acc, xch, Gtab, pair, lane, q, n, dch, A);
        else         finishDots<1>(acc, xch, Gtab, pair, lane, q, n, dch, A);
        __syncthreads();

        const float GA = Gtab[pair][n][0];
        const float GK = Gtab[pair][n][1];
        const float GT = Gtab[pair][n][2];
        float gA = fmaf(rgA, A  - pA, cdc2 * GA)         + 2.0f * fminf(A,  0.f);
        float gK = fmaf(rgK, K  - pK, cdc2 * A * GK)     + 2.0f * fminf(K,  0.f);
        float gT = fmaf(rgT, T0 - pT, cdc2 * A * K * GT) + 2.0f * fminf(T0, 0.f);
        A  -= 0.1f * gA;
        K  -= 0.1f * gK;
        T0 -= 0.1f * gT;
    }

    if (hh == 0 && lane < 16) {
        out[mypix]          = A;
        out[NPIX + mypix]   = K;
        out[2*NPIX + mypix] = T0;
    }
}

// -------------------------------------------------------------- launch ------
extern "C" void kernel_launch(void* const* d_in, const int* in_sizes, int n_in,
                              void* d_out, int out_size, void* d_ws, size_t ws_size,
                              hipStream_t stream) {
    const float* ctc   = (const float*)d_in[0];
    const float* aif   = (const float*)d_in[1];
    const float* timev = (const float*)d_in[2];
    const float* eta   = (const float*)d_in[4];
    const float* lam   = (const float*)d_in[5];
    float* out = (float*)d_out;
    // ws layout: [0..8191]      f32x4 partials[512]
    //            [8192..10239]  float tshg[512]
    //            [10240..54271] i32x4 Bg[NSLOT*64]
    f32x4* partials = (f32x4*)d_ws;
    float* tshg     = (float*)((char*)d_ws + 8192);
    i32x4* Bg       = (i32x4*)((char*)d_ws + 10240);

    k_prep<<<NPIX / 32, 256, 0, stream>>>(ctc, aif, timev, eta,
                                          tshg, Bg, partials);
    k_iter<<<NPIX / 32, 256, 0, stream>>>(ctc, lam, eta, tshg, Bg,
                                          partials, out);
}